// Round 9
// baseline (405.757 us; speedup 1.0000x reference)
//
#include <hip/hip_runtime.h>
#include <hip/hip_bf16.h>
#include <math.h>
#include <stdint.h>

typedef __bf16 bf16_t;
typedef __bf16 bf16x4 __attribute__((ext_vector_type(4)));
typedef __bf16 bf16x8 __attribute__((ext_vector_type(8)));
typedef float floatx4 __attribute__((ext_vector_type(4)));

#define BM 128
#define BK 32

__device__ __forceinline__ void gload16(const void* g, void* lds) {
    __builtin_amdgcn_global_load_lds(
        (__attribute__((address_space(1))) void*)(uintptr_t)g,
        (__attribute__((address_space(3))) void*)(uintptr_t)lds,
        16, 0, 0);
}

// ---------------- merged transpose + cast fp32 -> bf16 -------------------
__global__ void transpose_all(const float* __restrict__ wq, const float* __restrict__ wk,
                              const float* __restrict__ wv, const float* __restrict__ w_proj,
                              const float* __restrict__ w1, const float* __restrict__ w2,
                              bf16_t* __restrict__ WQKVT, bf16_t* __restrict__ WPROJT,
                              bf16_t* __restrict__ W1T, bf16_t* __restrict__ W2T)
{
    const int idx = blockIdx.x;
    const float* in; bf16_t* out; int R, C, rt, ct;
    if (idx < 768) {                       // wq/wk/wv: [16][1024][64] -> [64][1024] per head
        const int z = idx >> 8;
        const int hd = (idx >> 4) & 15;
        rt = idx & 15; ct = 0; R = 1024; C = 64;
        in  = (z == 0 ? wq : z == 1 ? wk : wv) + hd * 65536;
        out = WQKVT + z * (1 << 20) + hd * 65536;
    } else if (idx < 1024) {               // w_proj: [1024][1024]
        const int t = idx - 768; rt = t & 15; ct = t >> 4; R = 1024; C = 1024;
        in = w_proj; out = WPROJT;
    } else if (idx < 2048) {               // w1: [1024][4096]
        const int t = idx - 1024; rt = t & 15; ct = t >> 4; R = 1024; C = 4096;
        in = w1; out = W1T;
    } else {                               // w2: [4096][1024]
        const int t = idx - 2048; rt = t & 63; ct = t >> 6; R = 4096; C = 1024;
        in = w2; out = W2T;
    }
    __shared__ float tile[64][65];
    const int tid = threadIdx.x;
    const int r0 = rt * 64, c0 = ct * 64;
    const int tr = tid >> 4;
    const int tc = (tid & 15) * 4;
#pragma unroll
    for (int rr = 0; rr < 4; rr++) {
        const int r = tr + rr * 16;
        const float4 v = *(const float4*)&in[(long)(r0 + r) * C + c0 + tc];
        tile[r][tc + 0] = v.x; tile[r][tc + 1] = v.y;
        tile[r][tc + 2] = v.z; tile[r][tc + 3] = v.w;
    }
    __syncthreads();
#pragma unroll
    for (int rr = 0; rr < 4; rr++) {
        const int c = tr + rr * 16;
        bf16x4 o;
        o[0] = (bf16_t)tile[tc + 0][c];
        o[1] = (bf16_t)tile[tc + 1][c];
        o[2] = (bf16_t)tile[tc + 2][c];
        o[3] = (bf16_t)tile[tc + 3][c];
        *(bf16x4*)&out[(long)(c0 + c) * R + r0 + tc] = o;
    }
}

// ---------------- layernorm (fp32 in, bf16 out) --------------------------
__global__ void ln_kernel(const float* __restrict__ x, const float* __restrict__ g,
                          const float* __restrict__ b, bf16_t* __restrict__ outb)
{
    const int row = blockIdx.x;
    const int tid = threadIdx.x;
    const float4 v = ((const float4*)(x + (long)row * 1024))[tid];
    float s  = v.x + v.y + v.z + v.w;
    float s2 = v.x * v.x + v.y * v.y + v.z * v.z + v.w * v.w;
#pragma unroll
    for (int off = 32; off >= 1; off >>= 1) {
        s  += __shfl_xor(s, off);
        s2 += __shfl_xor(s2, off);
    }
    __shared__ float red[8];
    const int wv = tid >> 6;
    if ((tid & 63) == 0) { red[wv] = s; red[4 + wv] = s2; }
    __syncthreads();
    s  = red[0] + red[1] + red[2] + red[3];
    s2 = red[4] + red[5] + red[6] + red[7];
    const float mu  = s * (1.0f / 1024.0f);
    const float var = fmaxf(s2 * (1.0f / 1024.0f) - mu * mu, 0.0f);
    const float rs  = rsqrtf(var + 1e-5f);
    const float4 gv = ((const float4*)g)[tid];
    const float4 bv = ((const float4*)b)[tid];
    bf16x4 o;
    o[0] = (bf16_t)((v.x - mu) * rs * gv.x + bv.x);
    o[1] = (bf16_t)((v.y - mu) * rs * gv.y + bv.y);
    o[2] = (bf16_t)((v.z - mu) * rs * gv.z + bv.z);
    o[3] = (bf16_t)((v.w - mu) * rs * gv.w + bv.w);
    ((bf16x4*)(outb + (long)row * 1024))[tid] = o;
}

// ---------------- double layernorm fused: ln(ln(x)) -> bf16 ---------------
__global__ void ln2x_kernel(const float* __restrict__ x, const float* __restrict__ g,
                            const float* __restrict__ b, bf16_t* __restrict__ outb)
{
    const int row = blockIdx.x;
    const int tid = threadIdx.x;
    const float4 v = ((const float4*)(x + (long)row * 1024))[tid];
    float s  = v.x + v.y + v.z + v.w;
    float s2 = v.x * v.x + v.y * v.y + v.z * v.z + v.w * v.w;
#pragma unroll
    for (int off = 32; off >= 1; off >>= 1) {
        s  += __shfl_xor(s, off);
        s2 += __shfl_xor(s2, off);
    }
    __shared__ float red[8];
    __shared__ float red2[8];
    const int wv = tid >> 6;
    if ((tid & 63) == 0) { red[wv] = s; red[4 + wv] = s2; }
    __syncthreads();
    s  = red[0] + red[1] + red[2] + red[3];
    s2 = red[4] + red[5] + red[6] + red[7];
    float mu  = s * (1.0f / 1024.0f);
    float var = fmaxf(s2 * (1.0f / 1024.0f) - mu * mu, 0.0f);
    float rs  = rsqrtf(var + 1e-5f);
    const float4 gv = ((const float4*)g)[tid];
    const float4 bv = ((const float4*)b)[tid];
    float y0 = (v.x - mu) * rs * gv.x + bv.x;
    float y1 = (v.y - mu) * rs * gv.y + bv.y;
    float y2 = (v.z - mu) * rs * gv.z + bv.z;
    float y3 = (v.w - mu) * rs * gv.w + bv.w;
    s  = y0 + y1 + y2 + y3;
    s2 = y0 * y0 + y1 * y1 + y2 * y2 + y3 * y3;
#pragma unroll
    for (int off = 32; off >= 1; off >>= 1) {
        s  += __shfl_xor(s, off);
        s2 += __shfl_xor(s2, off);
    }
    if ((tid & 63) == 0) { red2[wv] = s; red2[4 + wv] = s2; }
    __syncthreads();
    s  = red2[0] + red2[1] + red2[2] + red2[3];
    s2 = red2[4] + red2[5] + red2[6] + red2[7];
    mu  = s * (1.0f / 1024.0f);
    var = fmaxf(s2 * (1.0f / 1024.0f) - mu * mu, 0.0f);
    rs  = rsqrtf(var + 1e-5f);
    bf16x4 o;
    o[0] = (bf16_t)((y0 - mu) * rs * gv.x + bv.x);
    o[1] = (bf16_t)((y1 - mu) * rs * gv.y + bv.y);
    o[2] = (bf16_t)((y2 - mu) * rs * gv.z + bv.z);
    o[3] = (bf16_t)((y3 - mu) * rs * gv.w + bv.w);
    ((bf16x4*)(outb + (long)row * 1024))[tid] = o;
}

// ---------------- bf16 MFMA GEMM: C = A[M,K] * Bt[N,K]^T -----------------
// R6 pipeline (triple-buffered gload16, fine vmcnt + raw s_barrier) with a
// CHUNK-MAJOR LDS layout: lane L of each gload16 sources global element
// [row = L&15][kchunk = L>>4], so LDS chunk L *is* the MFMA fragment chunk.
// Fragment reads become base + lane*16B — linear, conflict-free (R6's
// row-major layout had 8-way bank conflicts: 6.3M SQ_LDS_BANK_CONFLICT,
// ~2.9x LDS slowdown = the observed GEMM wall).
// EPI: 0=QKV scatter, 1=proj(+bias+resid->f32), 2=relu(+bias)->bf16, 3=final(+bias+resid)->f32
template<int EPI, int BNt>
__global__ __launch_bounds__(256, 2)
void gemm_bt(const bf16_t* __restrict__ A, const bf16_t* __restrict__ Bt,
             const int K,
             const float* __restrict__ bias, const float* __restrict__ resid,
             float* __restrict__ outf, bf16_t* __restrict__ outb,
             bf16_t* __restrict__ aux1, bf16_t* __restrict__ aux2,
             const int Nout)
{
    constexpr int NFRAG = BNt / 16;
    // rowblock = 16 rows x 32 k = 512 elem (1024 B), chunk-major inside
    __shared__ __align__(16) bf16_t As[3][8 * 512];
    __shared__ __align__(16) bf16_t Bs[3][NFRAG * 512];
    const int tid  = threadIdx.x;
    const int wave = tid >> 6, lane = tid & 63;
    const int bm = blockIdx.x * BM, bn = blockIdx.y * BNt;
    const int fr = lane & 15, g = lane >> 4;

    floatx4 acc[2][NFRAG];
#pragma unroll
    for (int i = 0; i < 2; i++)
#pragma unroll
        for (int j = 0; j < NFRAG; j++) acc[i][j] = (floatx4){0.f, 0.f, 0.f, 0.f};

    // staging source: lane supplies (row=fr, kchunk=g) of its rowblock
    const bf16_t* gA0 = A + (size_t)(bm + wave * 32 + fr) * K + g * 8;
    const bf16_t* gA1 = gA0 + (size_t)16 * K;
    const bf16_t* gB0;
    const bf16_t* gB1 = nullptr;
    if (BNt == 128) {
        gB0 = Bt + (size_t)(bn + wave * 32 + fr) * K + g * 8;
        gB1 = gB0 + (size_t)16 * K;
    } else {
        gB0 = Bt + (size_t)(bn + wave * 16 + fr) * K + g * 8;
    }

    auto stage = [&](int t, int bu) {
        const size_t off = (size_t)t * BK;
        gload16(gA0 + off, &As[bu][(wave * 2 + 0) * 512]);
        gload16(gA1 + off, &As[bu][(wave * 2 + 1) * 512]);
        if (BNt == 128) {
            gload16(gB0 + off, &Bs[bu][(wave * 2 + 0) * 512]);
            gload16(gB1 + off, &Bs[bu][(wave * 2 + 1) * 512]);
        } else {
            gload16(gB0 + off, &Bs[bu][wave * 512]);
        }
    };

    auto compute = [&](int bu) {
        bf16x8 af[2], bfv[NFRAG];
#pragma unroll
        for (int i = 0; i < 2; i++)
            af[i] = *(const bf16x8*)&As[bu][(wave * 2 + i) * 512 + lane * 8];
#pragma unroll
        for (int j = 0; j < NFRAG; j++)
            bfv[j] = *(const bf16x8*)&Bs[bu][j * 512 + lane * 8];
#pragma unroll
        for (int i = 0; i < 2; i++)
#pragma unroll
            for (int j = 0; j < NFRAG; j++)
                acc[i][j] = __builtin_amdgcn_mfma_f32_16x16x32_bf16(af[i], bfv[j], acc[i][j], 0, 0, 0);
    };

    const int NT = K / BK;
    stage(0, 0);
    stage(1, 1);
    int bu = 0;
    for (int t = 0; t < NT - 1; ++t) {
        // wait for MY tile-t loads only; next tile's stay in flight
        if (BNt == 128) asm volatile("s_waitcnt vmcnt(4)\n\ts_barrier" ::: "memory");
        else            asm volatile("s_waitcnt vmcnt(3)\n\ts_barrier" ::: "memory");
        if (t + 2 < NT) stage(t + 2, (t + 2) % 3);
        compute(bu);
        bu = (bu + 1) % 3;
    }
    asm volatile("s_waitcnt vmcnt(0)\n\ts_barrier" ::: "memory");
    compute(bu);

    // epilogue: C/D layout row=(lane>>4)*4+r, col=lane&15
    const int er = (lane >> 4) * 4, ec = lane & 15;
#pragma unroll
    for (int i = 0; i < 2; i++) {
#pragma unroll
        for (int j = 0; j < NFRAG; j++) {
            const int col = bn + j * 16 + ec;
#pragma unroll
            for (int r = 0; r < 4; r++) {
                const int row = bm + wave * 32 + i * 16 + er + r;
                const float v = acc[i][j][r];
                if (EPI == 0) {
                    const int b = row >> 10, t = row & 1023;
                    if (col < 1024) {
                        const int h = col >> 6, d = col & 63;
                        outb[(size_t)((b * 16 + h) * 1024 + t) * 64 + d] = (bf16_t)v;
                    } else if (col < 2048) {
                        const int c2 = col - 1024, h = c2 >> 6, d = c2 & 63;
                        aux1[(size_t)((b * 16 + h) * 1024 + t) * 64 + d] = (bf16_t)v;
                    } else {
                        const int c2 = col - 2048, h = c2 >> 6, d = c2 & 63;
                        aux2[(size_t)((b * 16 + h) * 64 + d) * 1024 + t] = (bf16_t)v;
                    }
                } else if (EPI == 1 || EPI == 3) {
                    const size_t idx = (size_t)row * Nout + col;
                    outf[idx] = v + bias[col] + resid[idx];
                } else if (EPI == 2) {
                    const size_t idx = (size_t)row * Nout + col;
                    outb[idx] = (bf16_t)fmaxf(v + bias[col], 0.f);
                }
            }
        }
    }
}

// ---------------- flash attention: Q[BH,T,64], K[BH,T,64], Vt[BH,64,T] ----
__global__ __launch_bounds__(256, 4)
void attn_kernel(const bf16_t* __restrict__ Q, const bf16_t* __restrict__ Kg,
                 const bf16_t* __restrict__ Vt, bf16_t* __restrict__ Og)
{
    __shared__ __align__(16) bf16_t Ks[2][4096];
    __shared__ __align__(16) bf16_t Vs[2][4096];
    __shared__ __align__(16) bf16_t Ps[4][1024];
    const int tid = threadIdx.x, wave = tid >> 6, lane = tid & 63;
    const int bh = blockIdx.y;
    const int b = bh >> 4, h = bh & 15;
    const int q0 = blockIdx.x * 64 + wave * 16;
    const bf16_t* Qb = Q + (size_t)bh * 65536;
    const char* Kb = (const char*)(Kg + (size_t)bh * 65536);
    const char* Vb = (const char*)(Vt + (size_t)bh * 65536);
    const int fr = lane & 15, g = lane >> 4, fk = g * 8;

    const bf16x8 qf0 = *(const bf16x8*)&Qb[(size_t)(q0 + fr) * 64 + fk];
    const bf16x8 qf1 = *(const bf16x8*)&Qb[(size_t)(q0 + fr) * 64 + 32 + fk];

    floatx4 o[4];
#pragma unroll
    for (int dt = 0; dt < 4; dt++) o[dt] = (floatx4){0.f, 0.f, 0.f, 0.f};
    float lsum[4] = {0.f, 0.f, 0.f, 0.f};
    bf16_t* pw = &Ps[wave][0];
    const float sscale = 0.125f * 1.44269504088896f;

    auto stage = [&](int s0, int bu) {
#pragma unroll
        for (int t = 0; t < 2; t++) {
            const int j = wave * 2 + t;
            gload16(Kb + (size_t)(s0 + lane) * 128 + j * 16, &Ks[bu][j * 512]);
            gload16(Vb + (size_t)lane * 2048 + (size_t)s0 * 2 + j * 16, &Vs[bu][j * 512]);
        }
    };

    stage(0, 0);
    int bu = 0;
    for (int it = 0; it < 16; ++it) {
        __syncthreads();
        if (it < 15) stage((it + 1) * 64, bu ^ 1);
        const bf16_t* Kl = Ks[bu];
        const bf16_t* Vl = Vs[bu];

        floatx4 sacc[4];
#pragma unroll
        for (int ss = 0; ss < 4; ss++) sacc[ss] = (floatx4){0.f, 0.f, 0.f, 0.f};
#pragma unroll
        for (int c = 0; c < 2; c++) {
            const int ch = c * 4 + g;
            const bf16x8 qf = (c == 0) ? qf0 : qf1;
#pragma unroll
            for (int ss = 0; ss < 4; ss++) {
                const bf16x8 kf = *(const bf16x8*)&Kl[ch * 512 + (ss * 16 + fr) * 8];
                sacc[ss] = __builtin_amdgcn_mfma_f32_16x16x32_bf16(qf, kf, sacc[ss], 0, 0, 0);
            }
        }
#pragma unroll
        for (int ss = 0; ss < 4; ss++) {
#pragma unroll
            for (int r = 0; r < 4; r++) {
                const float p = __builtin_amdgcn_exp2f(sacc[ss][r] * sscale);
                lsum[r] += p;
                const int q = g * 4 + r;
                pw[(ss * 2 + (fr >> 3)) * 128 + q * 8 + (fr & 7)] = (bf16_t)p;
            }
        }
        asm volatile("s_waitcnt lgkmcnt(0)" ::: "memory");
#pragma unroll
        for (int c = 0; c < 2; c++) {
            const int ch = c * 4 + g;
            const bf16x8 pf = *(const bf16x8*)&pw[ch * 128 + fr * 8];
#pragma unroll
            for (int dt = 0; dt < 4; dt++) {
                const bf16x8 vf = *(const bf16x8*)&Vl[ch * 512 + (dt * 16 + fr) * 8];
                o[dt] = __builtin_amdgcn_mfma_f32_16x16x32_bf16(pf, vf, o[dt], 0, 0, 0);
            }
        }
        asm volatile("" ::: "memory");
        bu ^= 1;
    }
#pragma unroll
    for (int r = 0; r < 4; r++) {
        float l = lsum[r];
        l += __shfl_xor(l, 1);
        l += __shfl_xor(l, 2);
        l += __shfl_xor(l, 4);
        l += __shfl_xor(l, 8);
        lsum[r] = 1.0f / l;
    }
    const int t = q0 + g * 4;
#pragma unroll
    for (int dt = 0; dt < 4; dt++) {
#pragma unroll
        for (int r = 0; r < 4; r++) {
            const size_t idx = ((size_t)(b * 1024 + t + r)) * 1024 + h * 64 + dt * 16 + fr;
            Og[idx] = (bf16_t)(o[dt][r] * lsum[r]);
        }
    }
}

// -------------------------------------------------------------------------
extern "C" void kernel_launch(void* const* d_in, const int* in_sizes, int n_in,
                              void* d_out, int out_size, void* d_ws, size_t ws_size,
                              hipStream_t stream)
{
    const float* x      = (const float*)d_in[0];
    const float* wq     = (const float*)d_in[1];
    const float* wk     = (const float*)d_in[2];
    const float* wv     = (const float*)d_in[3];
    const float* w_proj = (const float*)d_in[4];
    const float* b_proj = (const float*)d_in[5];
    const float* w1     = (const float*)d_in[6];
    const float* b1     = (const float*)d_in[7];
    const float* w2     = (const float*)d_in[8];
    const float* b2     = (const float*)d_in[9];
    const float* g1     = (const float*)d_in[10];
    const float* be1    = (const float*)d_in[11];
    const float* g2     = (const float*)d_in[12];
    const float* be2    = (const float*)d_in[13];
    float* out = (float*)d_out;
    char* ws = (char*)d_ws;

    bf16_t* WQKVT = (bf16_t*)(ws + 0x0000000);  // [3072,1024] bf16, 6 MB
    bf16_t* WPROJT= (bf16_t*)(ws + 0x0600000);  // [1024,1024] bf16, 2 MB
    bf16_t* W1T   = (bf16_t*)(ws + 0x0800000);  // [4096,1024] bf16, 8 MB
    bf16_t* W2T   = (bf16_t*)(ws + 0x1000000);  // [1024,4096] bf16, 8 MB
    bf16_t* HB    = (bf16_t*)(ws + 0x1800000);  // ln1 out bf16, 8 MB
    bf16_t* Qb    = (bf16_t*)(ws + 0x2000000);  // [BH,T,64] bf16, 8 MB
    bf16_t* Kb    = (bf16_t*)(ws + 0x2800000);  // [BH,T,64] bf16, 8 MB
    bf16_t* Vtb   = (bf16_t*)(ws + 0x3000000);  // [BH,64,T] bf16, 8 MB
    bf16_t* AO    = (bf16_t*)(ws + 0x3800000);  // attn out bf16, 8 MB
    float*  X2    = (float*)(ws + 0x4000000);   // x+sa fp32, 16 MB
    bf16_t* TB    = (bf16_t*)(ws + 0x2800000);  // ln2(ln2) bf16 (reuses Kb), 8 MB
    bf16_t* FF1B  = (bf16_t*)(ws + 0x5000000);  // [4096,4096] bf16, 32 MB

    dim3 blk(256);
    transpose_all<<<3072, blk, 0, stream>>>(wq, wk, wv, w_proj, w1, w2,
                                            WQKVT, WPROJT, W1T, W2T);
    ln_kernel<<<4096, blk, 0, stream>>>(x, g1, be1, HB);
    gemm_bt<0, 128><<<dim3(32, 24), blk, 0, stream>>>(HB, WQKVT, 1024, nullptr, nullptr,
                                                      nullptr, Qb, Kb, Vtb, 3072);
    attn_kernel<<<dim3(16, 64), blk, 0, stream>>>(Qb, Kb, Vtb, AO);
    gemm_bt<1, 64><<<dim3(32, 16), blk, 0, stream>>>(AO, WPROJT, 1024, b_proj, x,
                                                     X2, nullptr, nullptr, nullptr, 1024);
    ln2x_kernel<<<4096, blk, 0, stream>>>(X2, g2, be2, TB);
    gemm_bt<2, 128><<<dim3(32, 32), blk, 0, stream>>>(TB, W1T, 1024, b1, nullptr,
                                                      nullptr, FF1B, nullptr, nullptr, 4096);
    gemm_bt<3, 64><<<dim3(32, 16), blk, 0, stream>>>(FF1B, W2T, 4096, b2, X2,
                                                     out, nullptr, nullptr, nullptr, 1024);
}

// Round 10
// 308.865 us; speedup vs baseline: 1.3137x; 1.3137x over previous
//
#include <hip/hip_runtime.h>
#include <hip/hip_bf16.h>
#include <math.h>
#include <stdint.h>

typedef __bf16 bf16_t;
typedef __bf16 bf16x4 __attribute__((ext_vector_type(4)));
typedef __bf16 bf16x8 __attribute__((ext_vector_type(8)));
typedef float floatx4 __attribute__((ext_vector_type(4)));

#define BM 128
#define BK 32

__device__ __forceinline__ void gload16(const void* g, void* lds) {
    __builtin_amdgcn_global_load_lds(
        (__attribute__((address_space(1))) void*)(uintptr_t)g,
        (__attribute__((address_space(3))) void*)(uintptr_t)lds,
        16, 0, 0);
}

// ---------------- merged transpose + cast fp32 -> bf16, FRAGMENT-TILED ---
// Output layout: W^T [N][K] stored as 16-row x 32-k tiles, chunk-major:
//   addr(n,k) = ((n>>4)*(K/32) + (k>>5))*512 + (((k>>3)&3)*16 + (n&15))*8 + (k&7)
// A gload16 of one tile is a contiguous 1024B burst AND lands in LDS in MFMA
// fragment order -> conflict-free B-fragment reads at lane*16.
__global__ void transpose_all(const float* __restrict__ wq, const float* __restrict__ wk,
                              const float* __restrict__ wv, const float* __restrict__ w_proj,
                              const float* __restrict__ w1, const float* __restrict__ w2,
                              bf16_t* __restrict__ WQKVT, bf16_t* __restrict__ WPROJT,
                              bf16_t* __restrict__ W1T, bf16_t* __restrict__ W2T)
{
    const int idx = blockIdx.x;
    const float* in; bf16_t* out; int R, C, rt, ct; long nrow0;
    if (idx < 768) {                       // wq/wk/wv: [16][1024][64] per head
        const int z = idx >> 8;
        const int hd = (idx >> 4) & 15;
        rt = idx & 15; ct = 0; R = 1024; C = 64;
        in  = (z == 0 ? wq : z == 1 ? wk : wv) + hd * 65536;
        out = WQKVT; nrow0 = z * 1024 + hd * 64;
    } else if (idx < 1024) {               // w_proj: [1024][1024]
        const int t = idx - 768; rt = t & 15; ct = t >> 4; R = 1024; C = 1024;
        in = w_proj; out = WPROJT; nrow0 = 0;
    } else if (idx < 2048) {               // w1: [1024][4096]
        const int t = idx - 1024; rt = t & 15; ct = t >> 4; R = 1024; C = 4096;
        in = w1; out = W1T; nrow0 = 0;
    } else {                               // w2: [4096][1024]
        const int t = idx - 2048; rt = t & 63; ct = t >> 6; R = 4096; C = 1024;
        in = w2; out = W2T; nrow0 = 0;
    }
    __shared__ float tile[64][65];
    const int tid = threadIdx.x;
    const int r0 = rt * 64, c0 = ct * 64;
    const int tr = tid >> 4;
    const int tc = (tid & 15) * 4;
#pragma unroll
    for (int rr = 0; rr < 4; rr++) {
        const int r = tr + rr * 16;
        const float4 v = *(const float4*)&in[(long)(r0 + r) * C + c0 + tc];
        tile[r][tc + 0] = v.x; tile[r][tc + 1] = v.y;
        tile[r][tc + 2] = v.z; tile[r][tc + 3] = v.w;
    }
    __syncthreads();
    const int KT = R >> 5;                 // K/32 (K of the GEMM = input rows R)
#pragma unroll
    for (int rr = 0; rr < 4; rr++) {
        const int c = tr + rr * 16;        // output row offset within 64-col tile
        const long n = nrow0 + c0 + c;     // global output row (N dim)
        const int k = r0 + tc;             // global k (4 consecutive, e in {0,4})
        bf16x4 o;
        o[0] = (bf16_t)tile[tc + 0][c];
        o[1] = (bf16_t)tile[tc + 1][c];
        o[2] = (bf16_t)tile[tc + 2][c];
        o[3] = (bf16_t)tile[tc + 3][c];
        const long addr = ((n >> 4) * KT + (k >> 5)) * 512
                        + (((k >> 3) & 3) * 16 + (n & 15)) * 8 + (k & 7);
        *(bf16x4*)&out[addr] = o;
    }
}

// ---------------- layernorm (fp32 in, bf16 out) --------------------------
__global__ void ln_kernel(const float* __restrict__ x, const float* __restrict__ g,
                          const float* __restrict__ b, bf16_t* __restrict__ outb)
{
    const int row = blockIdx.x;
    const int tid = threadIdx.x;
    const float4 v = ((const float4*)(x + (long)row * 1024))[tid];
    float s  = v.x + v.y + v.z + v.w;
    float s2 = v.x * v.x + v.y * v.y + v.z * v.z + v.w * v.w;
#pragma unroll
    for (int off = 32; off >= 1; off >>= 1) {
        s  += __shfl_xor(s, off);
        s2 += __shfl_xor(s2, off);
    }
    __shared__ float red[8];
    const int wv = tid >> 6;
    if ((tid & 63) == 0) { red[wv] = s; red[4 + wv] = s2; }
    __syncthreads();
    s  = red[0] + red[1] + red[2] + red[3];
    s2 = red[4] + red[5] + red[6] + red[7];
    const float mu  = s * (1.0f / 1024.0f);
    const float var = fmaxf(s2 * (1.0f / 1024.0f) - mu * mu, 0.0f);
    const float rs  = rsqrtf(var + 1e-5f);
    const float4 gv = ((const float4*)g)[tid];
    const float4 bv = ((const float4*)b)[tid];
    bf16x4 o;
    o[0] = (bf16_t)((v.x - mu) * rs * gv.x + bv.x);
    o[1] = (bf16_t)((v.y - mu) * rs * gv.y + bv.y);
    o[2] = (bf16_t)((v.z - mu) * rs * gv.z + bv.z);
    o[3] = (bf16_t)((v.w - mu) * rs * gv.w + bv.w);
    ((bf16x4*)(outb + (long)row * 1024))[tid] = o;
}

// ---------------- double layernorm fused: ln(ln(x)) -> bf16 ---------------
__global__ void ln2x_kernel(const float* __restrict__ x, const float* __restrict__ g,
                            const float* __restrict__ b, bf16_t* __restrict__ outb)
{
    const int row = blockIdx.x;
    const int tid = threadIdx.x;
    const float4 v = ((const float4*)(x + (long)row * 1024))[tid];
    float s  = v.x + v.y + v.z + v.w;
    float s2 = v.x * v.x + v.y * v.y + v.z * v.z + v.w * v.w;
#pragma unroll
    for (int off = 32; off >= 1; off >>= 1) {
        s  += __shfl_xor(s, off);
        s2 += __shfl_xor(s2, off);
    }
    __shared__ float red[8];
    __shared__ float red2[8];
    const int wv = tid >> 6;
    if ((tid & 63) == 0) { red[wv] = s; red[4 + wv] = s2; }
    __syncthreads();
    s  = red[0] + red[1] + red[2] + red[3];
    s2 = red[4] + red[5] + red[6] + red[7];
    float mu  = s * (1.0f / 1024.0f);
    float var = fmaxf(s2 * (1.0f / 1024.0f) - mu * mu, 0.0f);
    float rs  = rsqrtf(var + 1e-5f);
    const float4 gv = ((const float4*)g)[tid];
    const float4 bv = ((const float4*)b)[tid];
    float y0 = (v.x - mu) * rs * gv.x + bv.x;
    float y1 = (v.y - mu) * rs * gv.y + bv.y;
    float y2 = (v.z - mu) * rs * gv.z + bv.z;
    float y3 = (v.w - mu) * rs * gv.w + bv.w;
    s  = y0 + y1 + y2 + y3;
    s2 = y0 * y0 + y1 * y1 + y2 * y2 + y3 * y3;
#pragma unroll
    for (int off = 32; off >= 1; off >>= 1) {
        s  += __shfl_xor(s, off);
        s2 += __shfl_xor(s2, off);
    }
    if ((tid & 63) == 0) { red2[wv] = s; red2[4 + wv] = s2; }
    __syncthreads();
    s  = red2[0] + red2[1] + red2[2] + red2[3];
    s2 = red2[4] + red2[5] + red2[6] + red2[7];
    mu  = s * (1.0f / 1024.0f);
    var = fmaxf(s2 * (1.0f / 1024.0f) - mu * mu, 0.0f);
    rs  = rsqrtf(var + 1e-5f);
    bf16x4 o;
    o[0] = (bf16_t)((y0 - mu) * rs * gv.x + bv.x);
    o[1] = (bf16_t)((y1 - mu) * rs * gv.y + bv.y);
    o[2] = (bf16_t)((y2 - mu) * rs * gv.z + bv.z);
    o[3] = (bf16_t)((y3 - mu) * rs * gv.w + bv.w);
    ((bf16x4*)(outb + (long)row * 1024))[tid] = o;
}

// ---------------- bf16 MFMA GEMM: C = A[M,K] * Bt_tiled ------------------
// R6 pipeline (triple-buffered gload16, fine vmcnt + raw s_barrier).
// A: row-major global (R6 staging, coalesced quads; A-frag reads keep the
//    8-way conflict — only 2 reads/iter).
// B: FRAGMENT-TILED global (see transpose_all): gload16 = contiguous 1024B
//    burst; B-frag reads at lane*16 — conflict-free (was 8-way x NFRAG).
// EPI: 0=QKV scatter, 1=proj(+bias+resid->f32), 2=relu(+bias)->bf16, 3=final(+bias+resid)->f32
template<int EPI, int BNt>
__global__ __launch_bounds__(256, 2)
void gemm_bt(const bf16_t* __restrict__ A, const bf16_t* __restrict__ Bt,
             const int K,
             const float* __restrict__ bias, const float* __restrict__ resid,
             float* __restrict__ outf, bf16_t* __restrict__ outb,
             bf16_t* __restrict__ aux1, bf16_t* __restrict__ aux2,
             const int Nout)
{
    constexpr int NFRAG = BNt / 16;
    __shared__ __align__(16) bf16_t As[3][BM * BK];
    __shared__ __align__(16) bf16_t Bs[3][NFRAG * 512];
    const int tid  = threadIdx.x;
    const int wave = tid >> 6, lane = tid & 63;
    const int bm = blockIdx.x * BM, bn = blockIdx.y * BNt;

    floatx4 acc[2][NFRAG];
#pragma unroll
    for (int i = 0; i < 2; i++)
#pragma unroll
        for (int j = 0; j < NFRAG; j++) acc[i][j] = (floatx4){0.f, 0.f, 0.f, 0.f};

    // A staging: R6 row-major (quad-coalesced)
    const int srow  = lane >> 2;
    const int selem = (lane & 3) * 8;
    const bf16_t* gA0 = A + (size_t)(bm + wave * 32 + srow) * K + selem;
    const bf16_t* gA1 = gA0 + (size_t)16 * K;
    const int laOff0 = (wave * 32 + srow) * BK + selem;   // lane-linear region
    const int laOff1 = laOff0 + 16 * BK;
    // note: gload16 dst is wave-uniform base + lane*16; region base below:
    const int lA0 = (wave * 32) * BK;
    const int lA1 = (wave * 32 + 16) * BK;

    // B staging: fragment-tiled; rowblock nb, lane-contiguous 1024B
    const int KT = K >> 5;
    const bf16_t* gB0;
    const bf16_t* gB1 = nullptr;
    int lB0, lB1 = 0;
    if (BNt == 128) {
        gB0 = Bt + ((size_t)(bn / 16 + wave * 2 + 0) * KT) * 512 + lane * 8;
        gB1 = Bt + ((size_t)(bn / 16 + wave * 2 + 1) * KT) * 512 + lane * 8;
        lB0 = (wave * 2 + 0) * 512;
        lB1 = (wave * 2 + 1) * 512;
    } else {
        gB0 = Bt + ((size_t)(bn / 16 + wave) * KT) * 512 + lane * 8;
        lB0 = wave * 512;
    }

    const int fr = lane & 15;
    const int fk = (lane >> 4) * 8;

    auto stage = [&](int t, int bu) {
        const size_t offA = (size_t)t * BK;
        const size_t offB = (size_t)t * 512;
        gload16(gA0 + offA, (bf16_t*)As[bu] + lA0);
        gload16(gA1 + offA, (bf16_t*)As[bu] + lA1);
        gload16(gB0 + offB, (bf16_t*)Bs[bu] + lB0);
        if (BNt == 128) gload16(gB1 + offB, (bf16_t*)Bs[bu] + lB1);
    };

    auto compute = [&](int bu) {
        bf16x8 af[2], bfv[NFRAG];
#pragma unroll
        for (int i = 0; i < 2; i++)
            af[i] = *(const bf16x8*)&As[bu][(wave * 32 + i * 16 + fr) * BK + fk];
#pragma unroll
        for (int j = 0; j < NFRAG; j++)
            bfv[j] = *(const bf16x8*)&Bs[bu][j * 512 + lane * 8];
#pragma unroll
        for (int i = 0; i < 2; i++)
#pragma unroll
            for (int j = 0; j < NFRAG; j++)
                acc[i][j] = __builtin_amdgcn_mfma_f32_16x16x32_bf16(af[i], bfv[j], acc[i][j], 0, 0, 0);
    };

    const int NT = K / BK;
    stage(0, 0);
    stage(1, 1);
    int bu = 0;
    for (int t = 0; t < NT - 1; ++t) {
        if (BNt == 128) asm volatile("s_waitcnt vmcnt(4)\n\ts_barrier" ::: "memory");
        else            asm volatile("s_waitcnt vmcnt(3)\n\ts_barrier" ::: "memory");
        if (t + 2 < NT) stage(t + 2, (t + 2) % 3);
        compute(bu);
        bu = (bu + 1) % 3;
    }
    asm volatile("s_waitcnt vmcnt(0)\n\ts_barrier" ::: "memory");
    compute(bu);

    // epilogue: C/D layout row=(lane>>4)*4+r, col=lane&15
    const int er = (lane >> 4) * 4, ec = lane & 15;
#pragma unroll
    for (int i = 0; i < 2; i++) {
#pragma unroll
        for (int j = 0; j < NFRAG; j++) {
            const int col = bn + j * 16 + ec;
#pragma unroll
            for (int r = 0; r < 4; r++) {
                const int row = bm + wave * 32 + i * 16 + er + r;
                const float v = acc[i][j][r];
                if (EPI == 0) {
                    const int b = row >> 10, t = row & 1023;
                    if (col < 1024) {
                        const int h = col >> 6, d = col & 63;
                        outb[(size_t)((b * 16 + h) * 1024 + t) * 64 + d] = (bf16_t)v;
                    } else if (col < 2048) {
                        const int c2 = col - 1024, h = c2 >> 6, d = c2 & 63;
                        aux1[(size_t)((b * 16 + h) * 1024 + t) * 64 + d] = (bf16_t)v;
                    } else {
                        const int c2 = col - 2048, h = c2 >> 6, d = c2 & 63;
                        aux2[(size_t)((b * 16 + h) * 64 + d) * 1024 + t] = (bf16_t)v;
                    }
                } else if (EPI == 1 || EPI == 3) {
                    const size_t idx = (size_t)row * Nout + col;
                    outf[idx] = v + bias[col] + resid[idx];
                } else if (EPI == 2) {
                    const size_t idx = (size_t)row * Nout + col;
                    outb[idx] = (bf16_t)fmaxf(v + bias[col], 0.f);
                }
            }
        }
    }
}

// ---------------- flash attention: Q[BH,T,64], K[BH,T,64], Vt[BH,64,T] ----
__global__ __launch_bounds__(256, 4)
void attn_kernel(const bf16_t* __restrict__ Q, const bf16_t* __restrict__ Kg,
                 const bf16_t* __restrict__ Vt, bf16_t* __restrict__ Og)
{
    __shared__ __align__(16) bf16_t Ks[2][4096];
    __shared__ __align__(16) bf16_t Vs[2][4096];
    __shared__ __align__(16) bf16_t Ps[4][1024];
    const int tid = threadIdx.x, wave = tid >> 6, lane = tid & 63;
    const int bh = blockIdx.y;
    const int b = bh >> 4, h = bh & 15;
    const int q0 = blockIdx.x * 64 + wave * 16;
    const bf16_t* Qb = Q + (size_t)bh * 65536;
    const char* Kb = (const char*)(Kg + (size_t)bh * 65536);
    const char* Vb = (const char*)(Vt + (size_t)bh * 65536);
    const int fr = lane & 15, g = lane >> 4, fk = g * 8;

    const bf16x8 qf0 = *(const bf16x8*)&Qb[(size_t)(q0 + fr) * 64 + fk];
    const bf16x8 qf1 = *(const bf16x8*)&Qb[(size_t)(q0 + fr) * 64 + 32 + fk];

    floatx4 o[4];
#pragma unroll
    for (int dt = 0; dt < 4; dt++) o[dt] = (floatx4){0.f, 0.f, 0.f, 0.f};
    float lsum[4] = {0.f, 0.f, 0.f, 0.f};
    bf16_t* pw = &Ps[wave][0];
    const float sscale = 0.125f * 1.44269504088896f;

    auto stage = [&](int s0, int bu) {
#pragma unroll
        for (int t = 0; t < 2; t++) {
            const int j = wave * 2 + t;
            gload16(Kb + (size_t)(s0 + lane) * 128 + j * 16, &Ks[bu][j * 512]);
            gload16(Vb + (size_t)lane * 2048 + (size_t)s0 * 2 + j * 16, &Vs[bu][j * 512]);
        }
    };

    stage(0, 0);
    int bu = 0;
    for (int it = 0; it < 16; ++it) {
        __syncthreads();
        if (it < 15) stage((it + 1) * 64, bu ^ 1);
        const bf16_t* Kl = Ks[bu];
        const bf16_t* Vl = Vs[bu];

        floatx4 sacc[4];
#pragma unroll
        for (int ss = 0; ss < 4; ss++) sacc[ss] = (floatx4){0.f, 0.f, 0.f, 0.f};
#pragma unroll
        for (int c = 0; c < 2; c++) {
            const int ch = c * 4 + g;
            const bf16x8 qf = (c == 0) ? qf0 : qf1;
#pragma unroll
            for (int ss = 0; ss < 4; ss++) {
                const bf16x8 kf = *(const bf16x8*)&Kl[ch * 512 + (ss * 16 + fr) * 8];
                sacc[ss] = __builtin_amdgcn_mfma_f32_16x16x32_bf16(qf, kf, sacc[ss], 0, 0, 0);
            }
        }
#pragma unroll
        for (int ss = 0; ss < 4; ss++) {
#pragma unroll
            for (int r = 0; r < 4; r++) {
                const float p = __builtin_amdgcn_exp2f(sacc[ss][r] * sscale);
                lsum[r] += p;
                const int q = g * 4 + r;
                pw[(ss * 2 + (fr >> 3)) * 128 + q * 8 + (fr & 7)] = (bf16_t)p;
            }
        }
        asm volatile("s_waitcnt lgkmcnt(0)" ::: "memory");
#pragma unroll
        for (int c = 0; c < 2; c++) {
            const int ch = c * 4 + g;
            const bf16x8 pf = *(const bf16x8*)&pw[ch * 128 + fr * 8];
#pragma unroll
            for (int dt = 0; dt < 4; dt++) {
                const bf16x8 vf = *(const bf16x8*)&Vl[ch * 512 + (dt * 16 + fr) * 8];
                o[dt] = __builtin_amdgcn_mfma_f32_16x16x32_bf16(pf, vf, o[dt], 0, 0, 0);
            }
        }
        asm volatile("" ::: "memory");
        bu ^= 1;
    }
#pragma unroll
    for (int r = 0; r < 4; r++) {
        float l = lsum[r];
        l += __shfl_xor(l, 1);
        l += __shfl_xor(l, 2);
        l += __shfl_xor(l, 4);
        l += __shfl_xor(l, 8);
        lsum[r] = 1.0f / l;
    }
    const int t = q0 + g * 4;
#pragma unroll
    for (int dt = 0; dt < 4; dt++) {
#pragma unroll
        for (int r = 0; r < 4; r++) {
            const size_t idx = ((size_t)(b * 1024 + t + r)) * 1024 + h * 64 + dt * 16 + fr;
            Og[idx] = (bf16_t)(o[dt][r] * lsum[r]);
        }
    }
}

// -------------------------------------------------------------------------
extern "C" void kernel_launch(void* const* d_in, const int* in_sizes, int n_in,
                              void* d_out, int out_size, void* d_ws, size_t ws_size,
                              hipStream_t stream)
{
    const float* x      = (const float*)d_in[0];
    const float* wq     = (const float*)d_in[1];
    const float* wk     = (const float*)d_in[2];
    const float* wv     = (const float*)d_in[3];
    const float* w_proj = (const float*)d_in[4];
    const float* b_proj = (const float*)d_in[5];
    const float* w1     = (const float*)d_in[6];
    const float* b1     = (const float*)d_in[7];
    const float* w2     = (const float*)d_in[8];
    const float* b2     = (const float*)d_in[9];
    const float* g1     = (const float*)d_in[10];
    const float* be1    = (const float*)d_in[11];
    const float* g2     = (const float*)d_in[12];
    const float* be2    = (const float*)d_in[13];
    float* out = (float*)d_out;
    char* ws = (char*)d_ws;

    bf16_t* WQKVT = (bf16_t*)(ws + 0x0000000);  // [3072,1024] bf16 tiled, 6 MB
    bf16_t* WPROJT= (bf16_t*)(ws + 0x0600000);  // [1024,1024] bf16 tiled, 2 MB
    bf16_t* W1T   = (bf16_t*)(ws + 0x0800000);  // [4096,1024] bf16 tiled, 8 MB
    bf16_t* W2T   = (bf16_t*)(ws + 0x1000000);  // [1024,4096] bf16 tiled, 8 MB
    bf16_t* HB    = (bf16_t*)(ws + 0x1800000);  // ln1 out bf16, 8 MB
    bf16_t* Qb    = (bf16_t*)(ws + 0x2000000);  // [BH,T,64] bf16, 8 MB
    bf16_t* Kb    = (bf16_t*)(ws + 0x2800000);  // [BH,T,64] bf16, 8 MB
    bf16_t* Vtb   = (bf16_t*)(ws + 0x3000000);  // [BH,64,T] bf16, 8 MB
    bf16_t* AO    = (bf16_t*)(ws + 0x3800000);  // attn out bf16, 8 MB
    float*  X2    = (float*)(ws + 0x4000000);   // x+sa fp32, 16 MB
    bf16_t* TB    = (bf16_t*)(ws + 0x2800000);  // ln2(ln2) bf16 (reuses Kb), 8 MB
    bf16_t* FF1B  = (bf16_t*)(ws + 0x5000000);  // [4096,4096] bf16, 32 MB

    dim3 blk(256);
    transpose_all<<<3072, blk, 0, stream>>>(wq, wk, wv, w_proj, w1, w2,
                                            WQKVT, WPROJT, W1T, W2T);
    ln_kernel<<<4096, blk, 0, stream>>>(x, g1, be1, HB);
    gemm_bt<0, 128><<<dim3(32, 24), blk, 0, stream>>>(HB, WQKVT, 1024, nullptr, nullptr,
                                                      nullptr, Qb, Kb, Vtb, 3072);
    attn_kernel<<<dim3(16, 64), blk, 0, stream>>>(Qb, Kb, Vtb, AO);
    gemm_bt<1, 64><<<dim3(32, 16), blk, 0, stream>>>(AO, WPROJT, 1024, b_proj, x,
                                                     X2, nullptr, nullptr, nullptr, 1024);
    ln2x_kernel<<<4096, blk, 0, stream>>>(X2, g2, be2, TB);
    gemm_bt<2, 128><<<dim3(32, 32), blk, 0, stream>>>(TB, W1T, 1024, b1, nullptr,
                                                      nullptr, FF1B, nullptr, nullptr, 4096);
    gemm_bt<3, 64><<<dim3(32, 16), blk, 0, stream>>>(FF1B, W2T, 4096, b2, X2,
                                                     out, nullptr, nullptr, nullptr, 1024);
}